// Round 1
// baseline (514.510 us; speedup 1.0000x reference)
//
#include <hip/hip_runtime.h>

#define NT 512
#define NWAVE 8
#define PE 136      // WxT pitch (bf16 elems): rows h (80), cols e (128) + pad, 16B-aligned rows
#define PW1 104     // W1T pitch: rows j (48), cols h (96 used) + pad
#define PH 104      // h0 pitch: rows t (16), cols h (96 used: 80 live + 16 zero pad)

typedef __attribute__((ext_vector_type(8))) short short8;   // 8 x bf16 (4 VGPRs)
typedef __attribute__((ext_vector_type(4))) float f32x4;    // MFMA accumulator

__device__ __forceinline__ unsigned short f2b(float f) {
  unsigned int x = __float_as_uint(f);
  return (unsigned short)((x + 0x7fffu + ((x >> 16) & 1u)) >> 16);
}
__device__ __forceinline__ float sigmoidf(float x) {
  return __builtin_amdgcn_rcpf(1.0f + __expf(-x));
}
__device__ __forceinline__ short8 pack8(float4 a, float4 b) {
  short8 r;
  r[0] = (short)f2b(a.x); r[1] = (short)f2b(a.y); r[2] = (short)f2b(a.z); r[3] = (short)f2b(a.w);
  r[4] = (short)f2b(b.x); r[5] = (short)f2b(b.y); r[6] = (short)f2b(b.z); r[7] = (short)f2b(b.w);
  return r;
}
__device__ __forceinline__ short8 pack8q(float4 a, float4 b, float4 qa, float4 qb) {
  short8 r;  // bf16(k * q), product in f32 then single rounding
  r[0] = (short)f2b(a.x * qa.x); r[1] = (short)f2b(a.y * qa.y);
  r[2] = (short)f2b(a.z * qa.z); r[3] = (short)f2b(a.w * qa.w);
  r[4] = (short)f2b(b.x * qb.x); r[5] = (short)f2b(b.y * qb.y);
  r[6] = (short)f2b(b.z * qb.z); r[7] = (short)f2b(b.w * qb.w);
  return r;
}

// ---- precompute C[b][h] = b0[h] + sum_e q[b][e] * (W0a + W0c)[e][h] ----
__global__ __launch_bounds__(256, 2) void prep_c(
    const float* __restrict__ q, const float* __restrict__ W0,
    const float* __restrict__ b0, float* __restrict__ C, int B)
{
  __shared__ float Wac[64 * 80];
  __shared__ float qlds[32 * 64];
  const int bbase = blockIdx.x * 32, tid = threadIdx.x;
  for (int idx = tid; idx < 5120; idx += 256) {
    const int e = idx / 80, h = idx - e * 80;
    Wac[idx] = W0[e * 80 + h] + W0[(128 + e) * 80 + h];
  }
  for (int idx = tid; idx < 2048; idx += 256) {
    const int bl = idx >> 6, e = idx & 63;
    const int bg = bbase + bl;
    qlds[idx] = (bg < B) ? q[bg * 64 + e] : 0.0f;
  }
  __syncthreads();
  #pragma unroll
  for (int i = 0; i < 10; ++i) {
    const int idx = tid + i * 256;  // < 2560 = 32*80
    const int bl = idx / 80, h = idx - bl * 80;
    const int bg = bbase + bl;
    if (bg < B) {
      float acc = b0[h];
      #pragma unroll 8
      for (int e = 0; e < 64; ++e) acc += qlds[bl * 64 + e] * Wac[e * 80 + h];
      C[bg * 80 + h] = acc;
    }
  }
}

// ---- main: one WAVE per batch row, zero barriers in the tile loop ----
// 512 thr = 8 waves = 8 batches/block. Batch-independent 128-wide layer-1
// weight Wx = [[W0b - W0c],[W0d]] staged once per block; x = [k, k*q] built
// in-register from direct global key loads (depth-1 prefetch). h0 transpose
// is intra-wave LDS (same wave writes rows it reads -> lgkmcnt only).
// LDS 58.4 KB -> 2 blocks/CU -> 16 waves/CU, all 4096 batches resident.
__global__ __launch_bounds__(NT, 4) void din_attn_main(
    const float* __restrict__ q,
    const float* __restrict__ keys,
    const int* __restrict__ klen,
    const float* __restrict__ W0,
    const float* __restrict__ b0,
    const float* __restrict__ W1,
    const float* __restrict__ b1,
    const float* __restrict__ W2,
    const float* __restrict__ b2,
    float* __restrict__ out,
    const float* __restrict__ Cpre,
    int B)
{
  __shared__ __align__(16) unsigned short WxT[80 * PE];        // 21760 B  [h][e]
  __shared__ __align__(16) unsigned short W1T[48 * PW1];       //  9984 B  [j][h]
  __shared__ __align__(16) unsigned short h0s[NWAVE][16 * PH]; // 26624 B  per-wave [t][h]

  const int tid = threadIdx.x;

  // Wx[e][h]: e<64 -> W0b - W0c ; e in [64,128) -> W0d  (stored transposed)
  for (int idx = tid; idx < 128 * 80; idx += NT) {
    const int e = idx / 80, h = idx - e * 80;
    const float v = (e < 64)
        ? (W0[(64 + e) * 80 + h] - W0[(128 + e) * 80 + h])
        : W0[(128 + e) * 80 + h];   // == W0[(192 + (e-64))*80 + h]
    WxT[h * PE + e] = f2b(v);
  }
  // W1T[j][h], zero-padded (j>=40 or h>=80)
  for (int idx = tid; idx < 48 * PW1; idx += NT) {
    const int j = idx / PW1, h = idx - j * PW1;
    W1T[idx] = (j < 40 && h < 80) ? f2b(W1[h * 40 + j]) : (unsigned short)0;
  }
  // zero this wave's h0 K-pad cols 80..95 (never written in the loop)
  {
    const int w0i = tid >> 6, ln = tid & 63;
    for (int i = ln; i < 256; i += 64)
      h0s[w0i][(i >> 4) * PH + 80 + (i & 15)] = 0;
  }
  __syncthreads();   // the ONLY block-wide barrier

  const int wv = __builtin_amdgcn_readfirstlane(tid >> 6);  // scalar wave id
  const int lane = tid & 63;
  const int lm = lane & 15;        // A-row / D-col within tile
  const int quad = lane >> 4;      // k-group / D-row-group
  const int b = blockIdx.x * NWAVE + wv;
  if (b >= B) return;

  int L = klen[b];
  L = __builtin_amdgcn_readfirstlane(max(0, min(200, L)));
  unsigned short* h0 = h0s[wv];

  // q fragment values for k*q (16 f32 in 4 float4, matches e = quad*8(+32)+i)
  const float* qb = q + (size_t)b * 64;
  const float4* q4 = (const float4*)qb;
  const float4 q0 = q4[quad * 2],     q1 = q4[quad * 2 + 1];
  const float4 q2 = q4[8 + quad * 2], q3 = q4[8 + quad * 2 + 1];

  // folded layer-1 bias C[b][col] per lane (col = nt*16+lm)
  float cfv[5];
  if (Cpre != nullptr) {
    #pragma unroll
    for (int nt = 0; nt < 5; ++nt) cfv[nt] = Cpre[b * 80 + nt * 16 + lm];
  } else {  // slow fallback (no workspace)
    #pragma unroll
    for (int nt = 0; nt < 5; ++nt) cfv[nt] = b0[nt * 16 + lm];
    for (int e = 0; e < 64; ++e) {
      const float qv = qb[e];
      #pragma unroll
      for (int nt = 0; nt < 5; ++nt) {
        const int col = nt * 16 + lm;
        cfv[nt] += qv * (W0[e * 80 + col] + W0[(128 + e) * 80 + col]);
      }
    }
  }
  float b1v[3], w2v[3];
  #pragma unroll
  for (int nt = 0; nt < 3; ++nt) {
    const int col = nt * 16 + lm;
    b1v[nt] = (col < 40) ? b1[col] : 0.0f;
    w2v[nt] = (col < 40) ? W2[col] : 0.0f;
  }
  const float b2v = b2[0];

  const float* kb = keys + (size_t)b * 12800;
  float wacc = 0.0f;
  const int ntile = (L + 15) >> 4;

  const float4 z4 = {0.0f, 0.0f, 0.0f, 0.0f};
  float4 k0 = z4, k1 = z4, k2 = z4, k3 = z4;
  if (ntile > 0 && lm < L) {   // prefetch tile 0: row lm, e = quad*8(+32)..+7
    const float4* kp = (const float4*)(kb + (size_t)lm * 64);
    k0 = kp[quad * 2]; k1 = kp[quad * 2 + 1];
    k2 = kp[8 + quad * 2]; k3 = kp[8 + quad * 2 + 1];
  }

  for (int p = 0; p < ntile; ++p) {
    // build A fragments: x = [k (e 0..63), k*q (e 64..127)]
    const short8 a0  = pack8(k0, k1);
    const short8 a1  = pack8(k2, k3);
    const short8 aq0 = pack8q(k0, k1, q0, q1);
    const short8 aq1 = pack8q(k2, k3, q2, q3);

    // depth-1 prefetch of next tile's keys (latency hides under MFMA below)
    if (p + 1 < ntile) {
      const int t = ((p + 1) << 4) + lm;
      if (t < L) {
        const float4* kp = (const float4*)(kb + (size_t)t * 64);
        k0 = kp[quad * 2]; k1 = kp[quad * 2 + 1];
        k2 = kp[8 + quad * 2]; k3 = kp[8 + quad * 2 + 1];
      } else { k0 = k1 = k2 = k3 = z4; }
    }

    // ---- layer 1: h0[16x80] = sigmoid(x[16x128] @ Wx[128x80] + C) ----
    #pragma unroll
    for (int nt = 0; nt < 5; ++nt) {
      const int col = nt * 16 + lm;
      const unsigned short* wr = &WxT[col * PE + quad * 8];
      const short8 w0 = *(const short8*)(wr);
      const short8 w1 = *(const short8*)(wr + 32);
      const short8 w2 = *(const short8*)(wr + 64);
      const short8 w3 = *(const short8*)(wr + 96);
      f32x4 acc;
      acc[0] = cfv[nt]; acc[1] = cfv[nt]; acc[2] = cfv[nt]; acc[3] = cfv[nt];
      acc = __builtin_amdgcn_mfma_f32_16x16x32_bf16(a0,  w0, acc, 0, 0, 0);
      acc = __builtin_amdgcn_mfma_f32_16x16x32_bf16(a1,  w1, acc, 0, 0, 0);
      acc = __builtin_amdgcn_mfma_f32_16x16x32_bf16(aq0, w2, acc, 0, 0, 0);
      acc = __builtin_amdgcn_mfma_f32_16x16x32_bf16(aq1, w3, acc, 0, 0, 0);
      #pragma unroll
      for (int r = 0; r < 4; ++r)
        h0[(quad * 4 + r) * PH + col] = f2b(sigmoidf(acc[r]));
    }

    // ---- layer 2+3: intra-wave h0 roundtrip, NO barrier (rows are ours) ----
    const short8 ha0 = *(const short8*)&h0[lm * PH + quad * 8];
    const short8 ha1 = *(const short8*)&h0[lm * PH + 32 + quad * 8];
    const short8 ha2 = *(const short8*)&h0[lm * PH + 64 + quad * 8];
    float pd[4] = {0.0f, 0.0f, 0.0f, 0.0f};
    #pragma unroll
    for (int nt = 0; nt < 3; ++nt) {
      const int col = nt * 16 + lm;
      const unsigned short* wr = &W1T[col * PW1 + quad * 8];
      const short8 wb0 = *(const short8*)(wr);
      const short8 wb1 = *(const short8*)(wr + 32);
      const short8 wb2 = *(const short8*)(wr + 64);
      f32x4 acc;
      acc[0] = b1v[nt]; acc[1] = b1v[nt]; acc[2] = b1v[nt]; acc[3] = b1v[nt];
      acc = __builtin_amdgcn_mfma_f32_16x16x32_bf16(ha0, wb0, acc, 0, 0, 0);
      acc = __builtin_amdgcn_mfma_f32_16x16x32_bf16(ha1, wb1, acc, 0, 0, 0);
      acc = __builtin_amdgcn_mfma_f32_16x16x32_bf16(ha2, wb2, acc, 0, 0, 0);
      #pragma unroll
      for (int r = 0; r < 4; ++r) pd[r] += sigmoidf(acc[r]) * w2v[nt];
    }
    // reduce over the 16 col-lanes; butterfly leaves the sum in ALL lanes
    #pragma unroll
    for (int r = 0; r < 4; ++r) {
      pd[r] += __shfl_xor(pd[r], 1);
      pd[r] += __shfl_xor(pd[r], 2);
      pd[r] += __shfl_xor(pd[r], 4);
      pd[r] += __shfl_xor(pd[r], 8);
    }
    float sc[4];   // score rows 4*quad + r, held by every lane of the quad
    #pragma unroll
    for (int r = 0; r < 4; ++r) sc[r] = sigmoidf(pd[r] + b2v);

    // ---- epilogue: wacc[e=lane] += score[t] * keys[t][lane] (fp32, L1-hot) ----
    const int t0 = p << 4;
    const int nr = min(16, L - t0);
    const float* krow = kb + (size_t)t0 * 64 + lane;
    #pragma unroll
    for (int t = 0; t < 16; ++t) {
      if (t < nr) {  // wave-uniform branch
        const float sv = __shfl(sc[t & 3], ((t >> 2) << 4) + lm);
        wacc += sv * krow[(size_t)t * 64];
      }
    }
  }

  out[(size_t)b * 64 + lane] = wacc;   // per-wave batch: no cross-wave reduce
}

extern "C" void kernel_launch(void* const* d_in, const int* in_sizes, int n_in,
                              void* d_out, int out_size, void* d_ws, size_t ws_size,
                              hipStream_t stream) {
  const int B = in_sizes[2];
  const float* Cpre = nullptr;
  if (ws_size >= (size_t)B * 80 * sizeof(float)) {
    float* C = (float*)d_ws;
    prep_c<<<(B + 31) / 32, 256, 0, stream>>>(
        (const float*)d_in[0], (const float*)d_in[3], (const float*)d_in[4], C, B);
    Cpre = C;
  }
  din_attn_main<<<(B + NWAVE - 1) / NWAVE, NT, 0, stream>>>(
      (const float*)d_in[0], (const float*)d_in[1], (const int*)d_in[2],
      (const float*)d_in[3], (const float*)d_in[4], (const float*)d_in[5],
      (const float*)d_in[6], (const float*)d_in[7], (const float*)d_in[8],
      (float*)d_out, Cpre, B);
}

// Round 2
// 370.939 us; speedup vs baseline: 1.3870x; 1.3870x over previous
//
#include <hip/hip_runtime.h>

#define NT 512
#define NWAVE 8
#define PE 136      // WxT pitch (bf16 elems): rows h (80), cols e (128) + pad, 16B-aligned rows
#define PW1 104     // W1T pitch: rows j (48), cols h (96 used) + pad
#define PH 104      // h0 pitch: rows t (16), cols h (96 used: 80 live + 16 zero pad)

typedef __attribute__((ext_vector_type(8))) short short8;   // 8 x bf16 (4 VGPRs)
typedef __attribute__((ext_vector_type(4))) float f32x4;    // MFMA accumulator

__device__ __forceinline__ unsigned short f2b(float f) {
  unsigned int x = __float_as_uint(f);
  return (unsigned short)((x + 0x7fffu + ((x >> 16) & 1u)) >> 16);
}
__device__ __forceinline__ float sigmoidf(float x) {
  return __builtin_amdgcn_rcpf(1.0f + __expf(-x));
}
__device__ __forceinline__ short8 pack8(float4 a, float4 b) {
  short8 r;
  r[0] = (short)f2b(a.x); r[1] = (short)f2b(a.y); r[2] = (short)f2b(a.z); r[3] = (short)f2b(a.w);
  r[4] = (short)f2b(b.x); r[5] = (short)f2b(b.y); r[6] = (short)f2b(b.z); r[7] = (short)f2b(b.w);
  return r;
}
__device__ __forceinline__ short8 pack8q(float4 a, float4 b, float4 qa, float4 qb) {
  short8 r;  // bf16(k * q), product in f32 then single rounding
  r[0] = (short)f2b(a.x * qa.x); r[1] = (short)f2b(a.y * qa.y);
  r[2] = (short)f2b(a.z * qa.z); r[3] = (short)f2b(a.w * qa.w);
  r[4] = (short)f2b(b.x * qb.x); r[5] = (short)f2b(b.y * qb.y);
  r[6] = (short)f2b(b.z * qb.z); r[7] = (short)f2b(b.w * qb.w);
  return r;
}

// ---- precompute C[b][h] = b0[h] + sum_e q[b][e] * (W0a + W0c)[e][h] ----
__global__ __launch_bounds__(256, 2) void prep_c(
    const float* __restrict__ q, const float* __restrict__ W0,
    const float* __restrict__ b0, float* __restrict__ C, int B)
{
  __shared__ float Wac[64 * 80];
  __shared__ float qlds[32 * 64];
  const int bbase = blockIdx.x * 32, tid = threadIdx.x;
  for (int idx = tid; idx < 5120; idx += 256) {
    const int e = idx / 80, h = idx - e * 80;
    Wac[idx] = W0[e * 80 + h] + W0[(128 + e) * 80 + h];
  }
  for (int idx = tid; idx < 2048; idx += 256) {
    const int bl = idx >> 6, e = idx & 63;
    const int bg = bbase + bl;
    qlds[idx] = (bg < B) ? q[bg * 64 + e] : 0.0f;
  }
  __syncthreads();
  #pragma unroll
  for (int i = 0; i < 10; ++i) {
    const int idx = tid + i * 256;  // < 2560 = 32*80
    const int bl = idx / 80, h = idx - bl * 80;
    const int bg = bbase + bl;
    if (bg < B) {
      float acc = b0[h];
      #pragma unroll 8
      for (int e = 0; e < 64; ++e) acc += qlds[bl * 64 + e] * Wac[e * 80 + h];
      C[bg * 80 + h] = acc;
    }
  }
}

// ---- main: one WAVE per batch row, zero barriers in the tile loop ----
// 512 thr = 8 waves = 8 batches/block. Batch-independent 128-wide layer-1
// weight Wx = [[W0b - W0c],[W0d]] staged once per block; x = [k, k*q] built
// in-register from direct global key loads (depth-1 prefetch). h0 transpose
// is intra-wave LDS (same wave writes rows it reads -> lgkmcnt only).
// LDS 58.4 KB -> 2 blocks/CU -> 16 waves/CU.
// __launch_bounds__(512, 2): this toolchain treats arg2 CUDA-style as
// min-BLOCKS/CU (round-1 evidence: (512,4) -> 32 waves/CU -> 64-VGPR cap ->
// ~122 MB scratch spill traffic). 2 blocks * 8 waves = 16 waves/CU ->
// 128-VGPR cap, fits the ~100-reg demand with zero spill.
__global__ __launch_bounds__(NT, 2) void din_attn_main(
    const float* __restrict__ q,
    const float* __restrict__ keys,
    const int* __restrict__ klen,
    const float* __restrict__ W0,
    const float* __restrict__ b0,
    const float* __restrict__ W1,
    const float* __restrict__ b1,
    const float* __restrict__ W2,
    const float* __restrict__ b2,
    float* __restrict__ out,
    const float* __restrict__ Cpre,
    int B)
{
  __shared__ __align__(16) unsigned short WxT[80 * PE];        // 21760 B  [h][e]
  __shared__ __align__(16) unsigned short W1T[48 * PW1];       //  9984 B  [j][h]
  __shared__ __align__(16) unsigned short h0s[NWAVE][16 * PH]; // 26624 B  per-wave [t][h]

  const int tid = threadIdx.x;

  // Wx[e][h]: e<64 -> W0b - W0c ; e in [64,128) -> W0d  (stored transposed)
  for (int idx = tid; idx < 128 * 80; idx += NT) {
    const int e = idx / 80, h = idx - e * 80;
    const float v = (e < 64)
        ? (W0[(64 + e) * 80 + h] - W0[(128 + e) * 80 + h])
        : W0[(128 + e) * 80 + h];   // == W0[(192 + (e-64))*80 + h]
    WxT[h * PE + e] = f2b(v);
  }
  // W1T[j][h], zero-padded (j>=40 or h>=80)
  for (int idx = tid; idx < 48 * PW1; idx += NT) {
    const int j = idx / PW1, h = idx - j * PW1;
    W1T[idx] = (j < 40 && h < 80) ? f2b(W1[h * 40 + j]) : (unsigned short)0;
  }
  // zero this wave's h0 K-pad cols 80..95 (never written in the loop)
  {
    const int w0i = tid >> 6, ln = tid & 63;
    for (int i = ln; i < 256; i += 64)
      h0s[w0i][(i >> 4) * PH + 80 + (i & 15)] = 0;
  }
  __syncthreads();   // the ONLY block-wide barrier

  const int wv = __builtin_amdgcn_readfirstlane(tid >> 6);  // scalar wave id
  const int lane = tid & 63;
  const int lm = lane & 15;        // A-row / D-col within tile
  const int quad = lane >> 4;      // k-group / D-row-group
  const int b = blockIdx.x * NWAVE + wv;
  if (b >= B) return;

  int L = klen[b];
  L = __builtin_amdgcn_readfirstlane(max(0, min(200, L)));
  unsigned short* h0 = h0s[wv];

  // q fragment values for k*q (16 f32 in 4 float4, matches e = quad*8(+32)+i)
  const float* qb = q + (size_t)b * 64;
  const float4* q4 = (const float4*)qb;
  const float4 q0 = q4[quad * 2],     q1 = q4[quad * 2 + 1];
  const float4 q2 = q4[8 + quad * 2], q3 = q4[8 + quad * 2 + 1];

  // folded layer-1 bias C[b][col] per lane (col = nt*16+lm)
  float cfv[5];
  if (Cpre != nullptr) {
    #pragma unroll
    for (int nt = 0; nt < 5; ++nt) cfv[nt] = Cpre[b * 80 + nt * 16 + lm];
  } else {  // slow fallback (no workspace)
    #pragma unroll
    for (int nt = 0; nt < 5; ++nt) cfv[nt] = b0[nt * 16 + lm];
    for (int e = 0; e < 64; ++e) {
      const float qv = qb[e];
      #pragma unroll
      for (int nt = 0; nt < 5; ++nt) {
        const int col = nt * 16 + lm;
        cfv[nt] += qv * (W0[e * 80 + col] + W0[(128 + e) * 80 + col]);
      }
    }
  }
  float b1v[3], w2v[3];
  #pragma unroll
  for (int nt = 0; nt < 3; ++nt) {
    const int col = nt * 16 + lm;
    b1v[nt] = (col < 40) ? b1[col] : 0.0f;
    w2v[nt] = (col < 40) ? W2[col] : 0.0f;
  }
  const float b2v = b2[0];

  const float* kb = keys + (size_t)b * 12800;
  float wacc = 0.0f;
  const int ntile = (L + 15) >> 4;

  const float4 z4 = {0.0f, 0.0f, 0.0f, 0.0f};
  float4 k0 = z4, k1 = z4, k2 = z4, k3 = z4;
  if (ntile > 0 && lm < L) {   // prefetch tile 0: row lm, e = quad*8(+32)..+7
    const float4* kp = (const float4*)(kb + (size_t)lm * 64);
    k0 = kp[quad * 2]; k1 = kp[quad * 2 + 1];
    k2 = kp[8 + quad * 2]; k3 = kp[8 + quad * 2 + 1];
  }

  for (int p = 0; p < ntile; ++p) {
    // build A fragments: x = [k (e 0..63), k*q (e 64..127)]
    const short8 a0  = pack8(k0, k1);
    const short8 a1  = pack8(k2, k3);
    const short8 aq0 = pack8q(k0, k1, q0, q1);
    const short8 aq1 = pack8q(k2, k3, q2, q3);

    // depth-1 prefetch of next tile's keys (latency hides under MFMA below)
    if (p + 1 < ntile) {
      const int t = ((p + 1) << 4) + lm;
      if (t < L) {
        const float4* kp = (const float4*)(kb + (size_t)t * 64);
        k0 = kp[quad * 2]; k1 = kp[quad * 2 + 1];
        k2 = kp[8 + quad * 2]; k3 = kp[8 + quad * 2 + 1];
      } else { k0 = k1 = k2 = k3 = z4; }
    }

    // ---- layer 1: h0[16x80] = sigmoid(x[16x128] @ Wx[128x80] + C) ----
    #pragma unroll
    for (int nt = 0; nt < 5; ++nt) {
      const int col = nt * 16 + lm;
      const unsigned short* wr = &WxT[col * PE + quad * 8];
      const short8 w0 = *(const short8*)(wr);
      const short8 w1 = *(const short8*)(wr + 32);
      const short8 w2 = *(const short8*)(wr + 64);
      const short8 w3 = *(const short8*)(wr + 96);
      f32x4 acc;
      acc[0] = cfv[nt]; acc[1] = cfv[nt]; acc[2] = cfv[nt]; acc[3] = cfv[nt];
      acc = __builtin_amdgcn_mfma_f32_16x16x32_bf16(a0,  w0, acc, 0, 0, 0);
      acc = __builtin_amdgcn_mfma_f32_16x16x32_bf16(a1,  w1, acc, 0, 0, 0);
      acc = __builtin_amdgcn_mfma_f32_16x16x32_bf16(aq0, w2, acc, 0, 0, 0);
      acc = __builtin_amdgcn_mfma_f32_16x16x32_bf16(aq1, w3, acc, 0, 0, 0);
      #pragma unroll
      for (int r = 0; r < 4; ++r)
        h0[(quad * 4 + r) * PH + col] = f2b(sigmoidf(acc[r]));
    }

    // ---- layer 2+3: intra-wave h0 roundtrip, NO barrier (rows are ours) ----
    const short8 ha0 = *(const short8*)&h0[lm * PH + quad * 8];
    const short8 ha1 = *(const short8*)&h0[lm * PH + 32 + quad * 8];
    const short8 ha2 = *(const short8*)&h0[lm * PH + 64 + quad * 8];
    float pd[4] = {0.0f, 0.0f, 0.0f, 0.0f};
    #pragma unroll
    for (int nt = 0; nt < 3; ++nt) {
      const int col = nt * 16 + lm;
      const unsigned short* wr = &W1T[col * PW1 + quad * 8];
      const short8 wb0 = *(const short8*)(wr);
      const short8 wb1 = *(const short8*)(wr + 32);
      const short8 wb2 = *(const short8*)(wr + 64);
      f32x4 acc;
      acc[0] = b1v[nt]; acc[1] = b1v[nt]; acc[2] = b1v[nt]; acc[3] = b1v[nt];
      acc = __builtin_amdgcn_mfma_f32_16x16x32_bf16(ha0, wb0, acc, 0, 0, 0);
      acc = __builtin_amdgcn_mfma_f32_16x16x32_bf16(ha1, wb1, acc, 0, 0, 0);
      acc = __builtin_amdgcn_mfma_f32_16x16x32_bf16(ha2, wb2, acc, 0, 0, 0);
      #pragma unroll
      for (int r = 0; r < 4; ++r) pd[r] += sigmoidf(acc[r]) * w2v[nt];
    }
    // reduce over the 16 col-lanes; butterfly leaves the sum in ALL lanes
    #pragma unroll
    for (int r = 0; r < 4; ++r) {
      pd[r] += __shfl_xor(pd[r], 1);
      pd[r] += __shfl_xor(pd[r], 2);
      pd[r] += __shfl_xor(pd[r], 4);
      pd[r] += __shfl_xor(pd[r], 8);
    }
    float sc[4];   // score rows 4*quad + r, held by every lane of the quad
    #pragma unroll
    for (int r = 0; r < 4; ++r) sc[r] = sigmoidf(pd[r] + b2v);

    // ---- epilogue: wacc[e=lane] += score[t] * keys[t][lane] (fp32, L1-hot) ----
    const int t0 = p << 4;
    const int nr = min(16, L - t0);
    const float* krow = kb + (size_t)t0 * 64 + lane;
    #pragma unroll
    for (int t = 0; t < 16; ++t) {
      if (t < nr) {  // wave-uniform branch
        const float sv = __shfl(sc[t & 3], ((t >> 2) << 4) + lm);
        wacc += sv * krow[(size_t)t * 64];
      }
    }
  }

  out[(size_t)b * 64 + lane] = wacc;   // per-wave batch: no cross-wave reduce
}

extern "C" void kernel_launch(void* const* d_in, const int* in_sizes, int n_in,
                              void* d_out, int out_size, void* d_ws, size_t ws_size,
                              hipStream_t stream) {
  const int B = in_sizes[2];
  const float* Cpre = nullptr;
  if (ws_size >= (size_t)B * 80 * sizeof(float)) {
    float* C = (float*)d_ws;
    prep_c<<<(B + 31) / 32, 256, 0, stream>>>(
        (const float*)d_in[0], (const float*)d_in[3], (const float*)d_in[4], C, B);
    Cpre = C;
  }
  din_attn_main<<<(B + NWAVE - 1) / NWAVE, NT, 0, stream>>>(
      (const float*)d_in[0], (const float*)d_in[1], (const int*)d_in[2],
      (const float*)d_in[3], (const float*)d_in[4], (const float*)d_in[5],
      (const float*)d_in[6], (const float*)d_in[7], (const float*)d_in[8],
      (float*)d_out, Cpre, B);
}

// Round 3
// 370.749 us; speedup vs baseline: 1.3878x; 1.0005x over previous
//
#include <hip/hip_runtime.h>

#define NT 512
#define NWAVE 8
#define PE 136     // WxT pitch: 80 rows(h) x 128 cols(e) + pad; stride 272B -> <=2-way banks
#define PW1 88     // W1T pitch: 48 rows(j) x 80 cols(h); stride 176B -> <=2-way on reads
#define PH 88      // h0 pitch: 32 rows(t) x 80 cols(h); stride 176B -> 2-way reads, 4-way writes
#define UPB 7      // 32-row units per batch = ceil(200/32)
#define BPC 64     // batches per work-steal counter
#define SPC (BPC * UPB)   // 448 slots per counter

typedef __attribute__((ext_vector_type(8))) short short8;   // 8 x bf16 (4 VGPRs)
typedef __attribute__((ext_vector_type(4))) float f32x4;    // MFMA accumulator

__device__ __forceinline__ unsigned short f2b(float f) {
  unsigned int x = __float_as_uint(f);
  return (unsigned short)((x + 0x7fffu + ((x >> 16) & 1u)) >> 16);
}
__device__ __forceinline__ float sigmoidf(float x) {
  return __builtin_amdgcn_rcpf(1.0f + __expf(-x));
}
__device__ __forceinline__ short8 pack8(float4 a, float4 b) {
  short8 r;
  r[0] = (short)f2b(a.x); r[1] = (short)f2b(a.y); r[2] = (short)f2b(a.z); r[3] = (short)f2b(a.w);
  r[4] = (short)f2b(b.x); r[5] = (short)f2b(b.y); r[6] = (short)f2b(b.z); r[7] = (short)f2b(b.w);
  return r;
}
__device__ __forceinline__ short8 pack8q(float4 a, float4 b, float4 qa, float4 qb) {
  short8 r;  // bf16(k * q), product in f32 then single rounding
  r[0] = (short)f2b(a.x * qa.x); r[1] = (short)f2b(a.y * qa.y);
  r[2] = (short)f2b(a.z * qa.z); r[3] = (short)f2b(a.w * qa.w);
  r[4] = (short)f2b(b.x * qb.x); r[5] = (short)f2b(b.y * qb.y);
  r[6] = (short)f2b(b.z * qb.z); r[7] = (short)f2b(b.w * qb.w);
  return r;
}

// ---- precompute C[b][h] = b0[h] + sum_e q[b][e] * (W0a + W0c)[e][h] ----
__global__ __launch_bounds__(256, 2) void prep_c(
    const float* __restrict__ q, const float* __restrict__ W0,
    const float* __restrict__ b0, float* __restrict__ C, int B)
{
  __shared__ float Wac[64 * 80];
  __shared__ float qlds[32 * 64];
  const int bbase = blockIdx.x * 32, tid = threadIdx.x;
  for (int idx = tid; idx < 5120; idx += 256) {
    const int e = idx / 80, h = idx - e * 80;
    Wac[idx] = W0[e * 80 + h] + W0[(128 + e) * 80 + h];
  }
  for (int idx = tid; idx < 2048; idx += 256) {
    const int bl = idx >> 6, e = idx & 63;
    const int bg = bbase + bl;
    qlds[idx] = (bg < B) ? q[bg * 64 + e] : 0.0f;
  }
  __syncthreads();
  #pragma unroll
  for (int i = 0; i < 10; ++i) {
    const int idx = tid + i * 256;  // < 2560 = 32*80
    const int bl = idx / 80, h = idx - bl * 80;
    const int bg = bbase + bl;
    if (bg < B) {
      float acc = b0[h];
      #pragma unroll 8
      for (int e = 0; e < 64; ++e) acc += qlds[bl * 64 + e] * Wac[e * 80 + h];
      C[bg * 80 + h] = acc;
    }
  }
}

// ---- main: persistent waves, work-stealing over (batch, 32-row-unit) ----
// 512 blocks x 8 waves = 4096 persistent waves, 2 blocks/CU (LDS 74.5 KB).
// 64 atomic counters (128 B apart), counter c owns batches [64c,64c+64),
// slot s -> b_local = s&63, u = s>>6 (p-major: empty slots drain last).
// Per unit: 32 key rows as two 16x128 MFMA A-sets sharing one weight-fragment
// read (DS diet), intra-wave h0 LDS roundtrip, butterfly + LDS score
// broadcast, fused epilogue, one atomicAdd(out) per lane per unit.
__global__ __launch_bounds__(NT, 2) void din_attn_main(
    const float* __restrict__ q,
    const float* __restrict__ keys,
    const int* __restrict__ klen,
    const float* __restrict__ W0,
    const float* __restrict__ b0,
    const float* __restrict__ W1,
    const float* __restrict__ b1,
    const float* __restrict__ W2,
    const float* __restrict__ b2,
    float* __restrict__ out,
    const float* __restrict__ Cpre,
    unsigned int* __restrict__ ctrs,
    int B)
{
  __shared__ __align__(16) unsigned short WxT[80 * PE];        // 21760 B [h][e]
  __shared__ __align__(16) unsigned short W1T[48 * PW1];       //  8448 B [j][h]
  __shared__ __align__(16) unsigned short h0s[NWAVE][32 * PH]; // 45056 B per-wave [t][h]
  __shared__ __align__(16) float scb[NWAVE][32];               //  1024 B per-wave scores

  const int tid = threadIdx.x;

  // Wx[e][h]: e<64 -> W0b - W0c ; e in [64,128) -> W0d  (stored transposed)
  for (int idx = tid; idx < 128 * 80; idx += NT) {
    const int e = idx / 80, h = idx - e * 80;
    const float v = (e < 64)
        ? (W0[(64 + e) * 80 + h] - W0[(128 + e) * 80 + h])
        : W0[(128 + e) * 80 + h];   // == W0[(192 + (e-64))*80 + h]
    WxT[h * PE + e] = f2b(v);
  }
  // W1T[j][h], zero-padded (j>=40 or h>=80); only 80 h-cols stored
  for (int idx = tid; idx < 48 * PW1; idx += NT) {
    const int j = idx / PW1, h = idx - j * PW1;
    W1T[idx] = (j < 40 && h < 80) ? f2b(W1[h * 40 + j]) : (unsigned short)0;
  }
  __syncthreads();   // the ONLY block-wide barrier

  const int wv = __builtin_amdgcn_readfirstlane(tid >> 6);
  const int lane = tid & 63;
  const int lm = lane & 15;        // A-row / D-col within tile
  const int quad = lane >> 4;      // k-group / D-row-group
  const int gw = blockIdx.x * NWAVE + wv;
  unsigned short* h0 = h0s[wv];
  float* scl = scb[wv];

  // batch-independent layer-2/3 constants (per-lane, hoisted out of all loops)
  float b1v[3], w2v[3];
  #pragma unroll
  for (int nt = 0; nt < 3; ++nt) {
    const int col = nt * 16 + lm;
    b1v[nt] = (col < 40) ? b1[col] : 0.0f;
    w2v[nt] = (col < 40) ? W2[col] : 0.0f;
  }
  const float b2v = b2[0];
  const short8 z8 = {0, 0, 0, 0, 0, 0, 0, 0};
  const float4 z4 = {0.0f, 0.0f, 0.0f, 0.0f};

  // ---- one 32-row unit of batch b (rows u*32 .. u*32+31), L > u*32 ----
  auto unit = [&](int b, int u, int L) {
    const float4* q4 = (const float4*)(q + (size_t)b * 64);
    const float4 q0 = q4[quad * 2],     q1 = q4[quad * 2 + 1];
    const float4 q2 = q4[8 + quad * 2], q3 = q4[8 + quad * 2 + 1];

    float cfv[5];
    if (Cpre != nullptr) {
      #pragma unroll
      for (int nt = 0; nt < 5; ++nt) cfv[nt] = Cpre[b * 80 + nt * 16 + lm];
    } else {  // slow fallback (no workspace)
      #pragma unroll
      for (int nt = 0; nt < 5; ++nt) cfv[nt] = b0[nt * 16 + lm];
      for (int e = 0; e < 64; ++e) {
        const float qv = q[(size_t)b * 64 + e];
        #pragma unroll
        for (int nt = 0; nt < 5; ++nt)
          cfv[nt] += qv * (W0[e * 80 + nt * 16 + lm] + W0[(128 + e) * 80 + nt * 16 + lm]);
      }
    }

    const float* kb = keys + (size_t)b * 12800;
    const int t0 = u << 5;
    const int nr = min(32, L - t0);      // >= 1
    const bool two = nr > 16;            // wave-uniform: second 16-row set live?

    // set0 A-fragments: x = [k | k*q], rows t0+lm
    short8 a0, a1, aq0, aq1;
    {
      const int t = t0 + lm;
      float4 k0 = z4, k1 = z4, k2 = z4, k3 = z4;
      if (t < L) {
        const float4* kp = (const float4*)(kb + (size_t)t * 64);
        k0 = kp[quad * 2]; k1 = kp[quad * 2 + 1];
        k2 = kp[8 + quad * 2]; k3 = kp[8 + quad * 2 + 1];
      }
      a0 = pack8(k0, k1); a1 = pack8(k2, k3);
      aq0 = pack8q(k0, k1, q0, q1); aq1 = pack8q(k2, k3, q2, q3);
    }
    // set1 A-fragments, rows t0+16+lm
    short8 c0 = z8, c1 = z8, cq0 = z8, cq1 = z8;
    if (two) {
      const int t = t0 + 16 + lm;
      float4 k0 = z4, k1 = z4, k2 = z4, k3 = z4;
      if (t < L) {
        const float4* kp = (const float4*)(kb + (size_t)t * 64);
        k0 = kp[quad * 2]; k1 = kp[quad * 2 + 1];
        k2 = kp[8 + quad * 2]; k3 = kp[8 + quad * 2 + 1];
      }
      c0 = pack8(k0, k1); c1 = pack8(k2, k3);
      cq0 = pack8q(k0, k1, q0, q1); cq1 = pack8q(k2, k3, q2, q3);
    }

    // ---- layer 1: both sets share one weight-fragment read per nt ----
    #pragma unroll
    for (int nt = 0; nt < 5; ++nt) {
      const int col = nt * 16 + lm;
      const unsigned short* wr = &WxT[col * PE + quad * 8];
      const short8 w0 = *(const short8*)(wr);
      const short8 w1 = *(const short8*)(wr + 32);
      const short8 w2 = *(const short8*)(wr + 64);
      const short8 w3 = *(const short8*)(wr + 96);
      f32x4 acc;
      acc[0] = cfv[nt]; acc[1] = cfv[nt]; acc[2] = cfv[nt]; acc[3] = cfv[nt];
      acc = __builtin_amdgcn_mfma_f32_16x16x32_bf16(a0,  w0, acc, 0, 0, 0);
      acc = __builtin_amdgcn_mfma_f32_16x16x32_bf16(a1,  w1, acc, 0, 0, 0);
      acc = __builtin_amdgcn_mfma_f32_16x16x32_bf16(aq0, w2, acc, 0, 0, 0);
      acc = __builtin_amdgcn_mfma_f32_16x16x32_bf16(aq1, w3, acc, 0, 0, 0);
      #pragma unroll
      for (int r = 0; r < 4; ++r)
        h0[(quad * 4 + r) * PH + col] = f2b(sigmoidf(acc[r]));
      if (two) {
        f32x4 ac2;
        ac2[0] = cfv[nt]; ac2[1] = cfv[nt]; ac2[2] = cfv[nt]; ac2[3] = cfv[nt];
        ac2 = __builtin_amdgcn_mfma_f32_16x16x32_bf16(c0,  w0, ac2, 0, 0, 0);
        ac2 = __builtin_amdgcn_mfma_f32_16x16x32_bf16(c1,  w1, ac2, 0, 0, 0);
        ac2 = __builtin_amdgcn_mfma_f32_16x16x32_bf16(cq0, w2, ac2, 0, 0, 0);
        ac2 = __builtin_amdgcn_mfma_f32_16x16x32_bf16(cq1, w3, ac2, 0, 0, 0);
        #pragma unroll
        for (int r = 0; r < 4; ++r)
          h0[(16 + quad * 4 + r) * PH + col] = f2b(sigmoidf(ac2[r]));
      }
    }

    // ---- layer 2+3: intra-wave h0 roundtrip (lgkmcnt only, no barrier) ----
    // K=80 handled as 64 + masked 16: quads 2,3 contribute zero fragments.
    const short8 ha00 = *(const short8*)&h0[lm * PH + quad * 8];
    const short8 ha01 = *(const short8*)&h0[lm * PH + 32 + quad * 8];
    short8 ha02 = z8;
    if (quad < 2) ha02 = *(const short8*)&h0[lm * PH + 64 + quad * 8];
    short8 ha10 = z8, ha11 = z8, ha12 = z8;
    if (two) {
      ha10 = *(const short8*)&h0[(16 + lm) * PH + quad * 8];
      ha11 = *(const short8*)&h0[(16 + lm) * PH + 32 + quad * 8];
      if (quad < 2) ha12 = *(const short8*)&h0[(16 + lm) * PH + 64 + quad * 8];
    }
    float pd0[4] = {0, 0, 0, 0}, pd1[4] = {0, 0, 0, 0};
    #pragma unroll
    for (int nt = 0; nt < 3; ++nt) {
      const int col = nt * 16 + lm;
      const unsigned short* wr = &W1T[col * PW1 + quad * 8];
      const short8 wb0 = *(const short8*)(wr);
      const short8 wb1 = *(const short8*)(wr + 32);
      short8 wb2 = z8;
      if (quad < 2) wb2 = *(const short8*)(wr + 64);
      f32x4 acc;
      acc[0] = b1v[nt]; acc[1] = b1v[nt]; acc[2] = b1v[nt]; acc[3] = b1v[nt];
      acc = __builtin_amdgcn_mfma_f32_16x16x32_bf16(ha00, wb0, acc, 0, 0, 0);
      acc = __builtin_amdgcn_mfma_f32_16x16x32_bf16(ha01, wb1, acc, 0, 0, 0);
      acc = __builtin_amdgcn_mfma_f32_16x16x32_bf16(ha02, wb2, acc, 0, 0, 0);
      #pragma unroll
      for (int r = 0; r < 4; ++r) pd0[r] += sigmoidf(acc[r]) * w2v[nt];
      if (two) {
        f32x4 ac2;
        ac2[0] = b1v[nt]; ac2[1] = b1v[nt]; ac2[2] = b1v[nt]; ac2[3] = b1v[nt];
        ac2 = __builtin_amdgcn_mfma_f32_16x16x32_bf16(ha10, wb0, ac2, 0, 0, 0);
        ac2 = __builtin_amdgcn_mfma_f32_16x16x32_bf16(ha11, wb1, ac2, 0, 0, 0);
        ac2 = __builtin_amdgcn_mfma_f32_16x16x32_bf16(ha12, wb2, ac2, 0, 0, 0);
        #pragma unroll
        for (int r = 0; r < 4; ++r) pd1[r] += sigmoidf(ac2[r]) * w2v[nt];
      }
    }
    // reduce over the 16 col-lanes (butterfly within each quad group)
    #pragma unroll
    for (int r = 0; r < 4; ++r) {
      pd0[r] += __shfl_xor(pd0[r], 1);
      pd0[r] += __shfl_xor(pd0[r], 2);
      pd0[r] += __shfl_xor(pd0[r], 4);
      pd0[r] += __shfl_xor(pd0[r], 8);
    }
    if (two) {
      #pragma unroll
      for (int r = 0; r < 4; ++r) {
        pd1[r] += __shfl_xor(pd1[r], 1);
        pd1[r] += __shfl_xor(pd1[r], 2);
        pd1[r] += __shfl_xor(pd1[r], 4);
        pd1[r] += __shfl_xor(pd1[r], 8);
      }
    }
    // broadcast scores via per-wave LDS (8 masked writes + 8 vector reads,
    // replaces 32 shfls)
    if (lm == 0) {
      #pragma unroll
      for (int r = 0; r < 4; ++r) scl[quad * 4 + r] = sigmoidf(pd0[r] + b2v);
      if (two) {
        #pragma unroll
        for (int r = 0; r < 4; ++r) scl[16 + quad * 4 + r] = sigmoidf(pd1[r] + b2v);
      }
    }
    float4 sv[8];
    #pragma unroll
    for (int i = 0; i < 8; ++i) sv[i] = *(const float4*)&scl[i * 4];

    // ---- fused epilogue: wacc[e=lane] += score[t] * keys[t0+t][lane] ----
    const float* kcol = kb + (size_t)t0 * 64 + lane;
    float wacc = 0.0f;
    #pragma unroll
    for (int t = 0; t < 32; ++t) {
      if (t < nr) {   // wave-uniform; also guards OOB key rows (u=6)
        const int i = t >> 2, j = t & 3;
        const float s = (j == 0) ? sv[i].x : (j == 1) ? sv[i].y : (j == 2) ? sv[i].z : sv[i].w;
        wacc += s * kcol[(size_t)t * 64];
      }
    }
    atomicAdd(&out[(size_t)b * 64 + lane], wacc);
  };

  if (ctrs != nullptr) {
    // ---- dynamic: pop (b,u) slots from this wave-group's counter ----
    const int c = gw >> 6;                 // 64 waves per counter
    unsigned int* ctr = ctrs + (size_t)c * 32;   // 128 B apart
    unsigned int v0 = 0u;
    if (lane == 0) v0 = atomicAdd(ctr, 1u);
    int s = (int)__builtin_amdgcn_readfirstlane(v0);
    while (s < SPC) {
      unsigned int vn = 0u;
      if (lane == 0) vn = atomicAdd(ctr, 1u);   // pop-ahead: waited at loop end
      const int b = (c << 6) + (s & 63);
      const int u = s >> 6;                // p-major: empties cluster at tail
      if (b < B) {
        int L = klen[b];
        L = __builtin_amdgcn_readfirstlane(max(0, min(200, L)));
        if (u * 32 < L) unit(b, u, L);
      }
      s = (int)__builtin_amdgcn_readfirstlane(vn);
    }
  } else {
    // ---- static fallback (no workspace): wave owns batch gw ----
    const int b = gw;
    if (b < B) {
      int L = klen[b];
      L = __builtin_amdgcn_readfirstlane(max(0, min(200, L)));
      for (int u = 0; u * 32 < L; ++u) unit(b, u, L);
    }
  }
}

extern "C" void kernel_launch(void* const* d_in, const int* in_sizes, int n_in,
                              void* d_out, int out_size, void* d_ws, size_t ws_size,
                              hipStream_t stream) {
  const int B = in_sizes[2];
  const size_t csize = (size_t)B * 80 * sizeof(float);
  const int nctr = (B + BPC - 1) / BPC;
  const size_t ctrbytes = (size_t)nctr * 32 * sizeof(unsigned int);

  const float* Cpre = nullptr;
  unsigned int* ctrs = nullptr;
  size_t off = 0;
  if (ws_size >= csize) { Cpre = (const float*)d_ws; off = csize; }
  off = (off + 127) & ~(size_t)127;
  if (ws_size >= off + ctrbytes) {
    ctrs = (unsigned int*)((char*)d_ws + off);
    hipMemsetAsync(ctrs, 0, ctrbytes, stream);
  }
  hipMemsetAsync(d_out, 0, (size_t)out_size, stream);

  if (Cpre != nullptr) {
    prep_c<<<(B + 31) / 32, 256, 0, stream>>>(
        (const float*)d_in[0], (const float*)d_in[3], (const float*)d_in[4],
        (float*)d_ws, B);
  }
  din_attn_main<<<(B + NWAVE - 1) / NWAVE, NT, 0, stream>>>(
      (const float*)d_in[0], (const float*)d_in[1], (const int*)d_in[2],
      (const float*)d_in[3], (const float*)d_in[4], (const float*)d_in[5],
      (const float*)d_in[6], (const float*)d_in[7], (const float*)d_in[8],
      (float*)d_out, Cpre, ctrs, B);
}